// Round 6
// baseline (6289.235 us; speedup 1.0000x reference)
//
#include <hip/hip_runtime.h>

typedef unsigned short u16;
typedef __bf16 bf16x8 __attribute__((ext_vector_type(8)));
typedef float f32x4 __attribute__((ext_vector_type(4)));

#define NWG 256

__device__ __forceinline__ u16 f2bf(float f) {
  union { float f; unsigned u; } v; v.f = f;
  unsigned r = v.u + 0x7fffu + ((v.u >> 16) & 1u);
  return (u16)(r >> 16);
}
__device__ __forceinline__ float bf2f(u16 h) {
  union { unsigned u; float f; } v; v.u = ((unsigned)h) << 16;
  return v.f;
}
__device__ __forceinline__ float fsig(float x) { return 1.0f / (1.0f + __expf(-x)); }
__device__ __forceinline__ float ftanh(float x) {
  float a = fabsf(x);
  float e = __expf(2.0f * a);
  float t = 1.0f - 2.0f / (e + 1.0f);
  return copysignf(t, x);
}

// inputs [b][s][d] fp32 -> [s][b][d] bf16
__global__ __launch_bounds__(256) void k_cvt_in(const float* __restrict__ inp,
                                                u16* __restrict__ dst) {
  unsigned i = blockIdx.x * 256 + threadIdx.x;
  unsigned d8 = i & 63u;
  unsigned b = (i >> 6) & 63u;
  unsigned s = i >> 12;
  const float* src = inp + ((size_t)b * 512 + s) * 512 + (size_t)d8 * 8;
  float4 x0 = *(const float4*)src;
  float4 x1 = *(const float4*)(src + 4);
  union { u16 h[8]; uint4 v; } o;
  o.h[0] = f2bf(x0.x); o.h[1] = f2bf(x0.y); o.h[2] = f2bf(x0.z); o.h[3] = f2bf(x0.w);
  o.h[4] = f2bf(x1.x); o.h[5] = f2bf(x1.y); o.h[6] = f2bf(x1.z); o.h[7] = f2bf(x1.w);
  *(uint4*)(dst + ((size_t)s * 64 + b) * 512 + d8 * 8) = o.v;
}

// 4 gate matrices [K][1024] fp32 -> combined transposed [4096][K] bf16
__global__ __launch_bounds__(256) void k_cvt_w(const float* __restrict__ W0,
                                               const float* __restrict__ W1,
                                               const float* __restrict__ W2,
                                               const float* __restrict__ W3,
                                               int K, u16* __restrict__ dst) {
  unsigned i = blockIdx.x * 256 + threadIdx.x;
  unsigned kb = (unsigned)K >> 3;
  unsigned k8 = i % kb;
  unsigned n = i / kb;
  if (n >= 4096) return;
  unsigned gate = n >> 10, h = n & 1023u;
  const float* W = (gate == 0) ? W0 : (gate == 1) ? W1 : (gate == 2) ? W2 : W3;
  union { u16 hh[8]; uint4 v; } o;
#pragma unroll
  for (int q = 0; q < 8; ++q) o.hh[q] = f2bf(W[(size_t)(k8 * 8 + q) * 1024 + h]);
  *(uint4*)(dst + (size_t)n * K + k8 * 8) = o.v;
}

// zero the barrier region and init hbuf[0]
__global__ __launch_bounds__(256) void k_init(const float* __restrict__ H0,
                                              u16* __restrict__ hbuf,
                                              unsigned* __restrict__ bar) {
  unsigned i = blockIdx.x * 256 + threadIdx.x;
  if (i < 16384) bar[i] = 0u;
  if (i < 65536) hbuf[i] = f2bf(H0[i]);
}

// Xp GEMM: A [32768][512] bf16 (s,b-major), Bm [4096][512] bf16 (n-major) -> Xp [32768][4096] bf16
__global__ __launch_bounds__(256) void k_xp(const u16* __restrict__ A,
                                            const u16* __restrict__ Bm,
                                            u16* __restrict__ Xp) {
  __shared__ u16 Al[64][72];
  __shared__ u16 Bl[64][72];
  int t = threadIdx.x;
  int lane = t & 63, wid = t >> 6;
  int m0 = blockIdx.x * 64, n0 = blockIdx.y * 64;
  int quad = lane >> 4, l15 = lane & 15;
  f32x4 acc[4];
#pragma unroll
  for (int i = 0; i < 4; ++i) acc[i] = (f32x4){0.f, 0.f, 0.f, 0.f};
  int srow = t >> 2, sk = (t & 3) * 16;
  for (int kc = 0; kc < 512; kc += 64) {
    const u16* s1 = A + (size_t)(m0 + srow) * 512 + kc + sk;
    *(uint4*)&Al[srow][sk] = *(const uint4*)s1;
    *(uint4*)&Al[srow][sk + 8] = *(const uint4*)(s1 + 8);
    const u16* s2 = Bm + (size_t)(n0 + srow) * 512 + kc + sk;
    *(uint4*)&Bl[srow][sk] = *(const uint4*)s2;
    *(uint4*)&Bl[srow][sk + 8] = *(const uint4*)(s2 + 8);
    __syncthreads();
#pragma unroll
    for (int ks = 0; ks < 64; ks += 32) {
      bf16x8 a = *(const bf16x8*)&Al[wid * 16 + l15][ks + quad * 8];
#pragma unroll
      for (int nt = 0; nt < 4; ++nt) {
        bf16x8 b = *(const bf16x8*)&Bl[nt * 16 + l15][ks + quad * 8];
        acc[nt] = __builtin_amdgcn_mfma_f32_16x16x32_bf16(a, b, acc[nt], 0, 0, 0);
      }
    }
    __syncthreads();
  }
#pragma unroll
  for (int nt = 0; nt < 4; ++nt)
#pragma unroll
    for (int r = 0; r < 4; ++r) {
      size_t row = (size_t)m0 + wid * 16 + quad * 4 + r;  // C/D: row=quad*4+reg, col=lane&15
      Xp[row * 4096 + n0 + nt * 16 + l15] = f2bf(acc[nt][r]);
    }
}

// Persistent LSTM recurrence, batch-grouped: the LSTM recurrence is independent
// per batch row, so only WGs sharing a batch slice must sync. 8 groups x 32 WGs;
// group g owns batches [8g,8g+8); WG (g,wgi) owns h-cols [32*wgi,+32) x 4 gates.
// Wh slice (1024x128 = 256 KB bf16) is pinned in registers: 32 x bf16x8 per lane.
// A-operand read directly from global hbuf (L1-deduped, rows m and m+8 alias).
// Sync = fence-free 32-WG group barrier (sc1 flags at MALL; __syncthreads drains
// vmcnt; hbuf write-once-read-once => plain cached loads never stale).
template <int USE_XP>
__global__ __launch_bounds__(512, 2) void k_recur(
    u16* hbuf, const u16* __restrict__ whc, const u16* __restrict__ wxc,
    const u16* xp, const u16* inpb, const float* __restrict__ C0,
    const float* __restrict__ bi, const float* __restrict__ bff,
    const float* __restrict__ bo, const float* __restrict__ bc,
    float* __restrict__ dout, unsigned* bar) {
  int t = threadIdx.x;
  int wg = blockIdx.x;
  int g = wg >> 5;    // batch group: batches 8g..8g+7
  int wgi = wg & 31;  // WG's h-col slice within group
  int lane = t & 63;
  int w = t >> 6;  // wave 0..7: h-cols hc0..hc0+3
  int quad = lane >> 4;
  int ncol = lane & 15;
  int gate = ncol >> 2, hcl = ncol & 3;
  int hc0 = wgi * 32 + w * 4;

  unsigned* flags = bar;  // flags[wg] at bar[wg*32] (128B lines)

  __shared__ float gt[8][8][17];
  __shared__ float biasl[8][16];

  // ---- Wh fragments into registers (loop-invariant): wave's col n, all K ----
  int n = gate * 1024 + hc0 + hcl;  // gate-col for B-frag AND C/D col AND xp col
  bf16x8 wreg[32];
  {
    const u16* wb = whc + (size_t)n * 1024 + quad * 8;
#pragma unroll
    for (int ks = 0; ks < 32; ++ks) wreg[ks] = *(const bf16x8*)(wb + ks * 32);
  }
  bf16x8 wxreg[USE_XP ? 1 : 16];
  if (!USE_XP) {
    const u16* wb2 = wxc + (size_t)n * 512 + quad * 8;
#pragma unroll
    for (int ks = 0; ks < 16; ++ks) wxreg[ks] = *(const bf16x8*)(wb2 + ks * 32);
  }
  if (lane < 16) {
    const float* bp = (gate == 0) ? bi : (gate == 1) ? bff : (gate == 2) ? bo : bc;
    biasl[w][lane] = bp[hc0 + hcl];
  }
  // C-state: lane L<32 owns (batch-local bl=L>>2, h-col hc0+(L&3))
  int bl = (lane & 31) >> 2, jcl = lane & 3;
  int bg = 8 * g + bl;          // global batch for gate phase
  int hcg = hc0 + jcl;          // global h-col for gate phase
  float Creg = 0.f;
  if (lane < 32) Creg = C0[bg * 1024 + hcg];

  int ba = 8 * g + (ncol & 7);  // A-operand batch row (m=ncol; m>=8 duplicates)

  // xp prefetch (C/D rows quad*4+r, quad<2 valid)
  u16 xn0 = 0, xn1 = 0, xn2 = 0, xn3 = 0;
  const u16* xpc = 0;
  if (USE_XP) {
    xpc = xp + (size_t)(8 * g + quad * 4) * 4096 + n;
    if (quad < 2) {
      xn0 = xpc[0]; xn1 = xpc[4096]; xn2 = xpc[8192]; xn3 = xpc[12288];
    }
  }
  __syncthreads();

  const u16* hrow = hbuf + (size_t)ba * 1024 + quad * 8;
  for (int s = 0; s < 512; ++s) {
    f32x4 acc = (f32x4){0.f, 0.f, 0.f, 0.f};
    f32x4 acc2 = (f32x4){0.f, 0.f, 0.f, 0.f};
    if (USE_XP) {
      if (quad < 2) {
        acc[0] = bf2f(xn0); acc[1] = bf2f(xn1);
        acc[2] = bf2f(xn2); acc[3] = bf2f(xn3);
      }
    } else {
      const u16* irow = inpb + (size_t)s * 32768 + (size_t)ba * 512 + quad * 8;
#pragma unroll
      for (int ks = 0; ks < 16; ++ks) {
        bf16x8 a = *(const bf16x8*)(irow + ks * 32);
        if (ks & 1)
          acc2 = __builtin_amdgcn_mfma_f32_16x16x32_bf16(a, wxreg[ks], acc2, 0, 0, 0);
        else
          acc = __builtin_amdgcn_mfma_f32_16x16x32_bf16(a, wxreg[ks], acc, 0, 0, 0);
      }
    }
#pragma unroll
    for (int ks = 0; ks < 32; ++ks) {
      bf16x8 a = *(const bf16x8*)(hrow + ks * 32);
      if (ks & 1)
        acc2 = __builtin_amdgcn_mfma_f32_16x16x32_bf16(a, wreg[ks], acc2, 0, 0, 0);
      else
        acc = __builtin_amdgcn_mfma_f32_16x16x32_bf16(a, wreg[ks], acc, 0, 0, 0);
    }
    acc += acc2;
    hrow += 65536;
    // wave-local combine: C/D row=quad*4+r (batch-local, quad<2 valid), col=ncol
    if (quad < 2) {
#pragma unroll
      for (int r = 0; r < 4; ++r) gt[w][quad * 4 + r][ncol] = acc[r];
    }
    // gate phase (lanes 0..31 of each wave; wave-local LDS, no syncthreads)
    float Hn = 0.f, Cn = 0.f;
    if (lane < 32) {
      float gi = gt[w][bl][jcl] + biasl[w][jcl];
      float gf = gt[w][bl][4 + jcl] + biasl[w][4 + jcl];
      float go_ = gt[w][bl][8 + jcl] + biasl[w][8 + jcl];
      float gc = gt[w][bl][12 + jcl] + biasl[w][12 + jcl];
      float iv = fsig(gi), fv = fsig(gf), ov = fsig(go_), cv = ftanh(gc);
      Cn = fv * Creg + iv * cv;
      Creg = Cn;
      Hn = ov * ftanh(Cn);
    }
    unsigned hb = (unsigned)f2bf(Hn);
    unsigned up = (unsigned)__shfl_down((int)hb, 1, 64);
    if (lane < 32 && (jcl & 1) == 0) {
      unsigned pack = hb | (up << 16);
      unsigned* hp =
          (unsigned*)(hbuf + (size_t)(s + 1) * 65536 + bg * 1024 + hcg);
      __hip_atomic_store(hp, pack, __ATOMIC_RELAXED, __HIP_MEMORY_SCOPE_AGENT);
    }
    if (s == 511 && lane < 32) {
      dout[32768 + bg * 1024 + hcg] = Hn;   // Hf
      dout[98304 + bg * 1024 + hcg] = Cn;   // Cf
    }
    // ---- fence-free 32-WG group barrier ----
    unsigned s1 = (unsigned)(s + 1);
    __syncthreads();  // drains vmcnt: all H stores at the coherent point
    if (s1 < 512) {
      if (t == 0)
        __hip_atomic_store(&flags[wg * 32], s1, __ATOMIC_RELAXED,
                           __HIP_MEMORY_SCOPE_AGENT);
      if (USE_XP && quad < 2) {  // prefetch next xp while waiting
        const u16* xpp = xpc + (size_t)s1 * 262144;
        xn0 = xpp[0]; xn1 = xpp[4096]; xn2 = xpp[8192]; xn3 = xpp[12288];
      }
      __asm__ volatile("" ::: "memory");  // keep prefetch above the spin
      if (t < 32) {  // poll my group's 32 arrival flags
        while (__hip_atomic_load(&flags[(g * 32 + t) * 32], __ATOMIC_RELAXED,
                                 __HIP_MEMORY_SCOPE_AGENT) < s1)
          __builtin_amdgcn_s_sleep(1);
      }
      __syncthreads();
    }
  }
}

// pred[b][s] = H_t[b] . fc_W + fc_b   (one wave per row)
__global__ __launch_bounds__(256) void k_pred(const u16* __restrict__ hbuf,
                                              const float* __restrict__ fcW,
                                              const float* __restrict__ fcb,
                                              float* __restrict__ out) {
  __shared__ float wsm[1024];
  int t = threadIdx.x;
#pragma unroll
  for (int i = 0; i < 4; ++i) wsm[t + i * 256] = fcW[t + i * 256];
  __syncthreads();
  int wid = t >> 6, lane = t & 63;
  int row = blockIdx.x * 4 + wid;  // row = b*512 + s
  int b = row >> 9, s = row & 511;
  const u16* h = hbuf + (size_t)(s + 1) * 65536 + (size_t)b * 1024;
  float sum = 0.f;
#pragma unroll
  for (int it = 0; it < 16; ++it) {
    int hh = it * 64 + lane;
    sum += bf2f(h[hh]) * wsm[hh];
  }
#pragma unroll
  for (int o = 32; o > 0; o >>= 1) sum += __shfl_down(sum, o, 64);
  if (lane == 0) out[row] = sum + fcb[0];
}

extern "C" void kernel_launch(void* const* d_in, const int* in_sizes, int n_in,
                              void* d_out, int out_size, void* d_ws, size_t ws_size,
                              hipStream_t stream) {
  const float* inputs = (const float*)d_in[0];
  const float* H0 = (const float*)d_in[1];
  const float* C0 = (const float*)d_in[2];
  const float* Wxi = (const float*)d_in[3];
  const float* Whi = (const float*)d_in[4];
  const float* bi = (const float*)d_in[5];
  const float* Wxf = (const float*)d_in[6];
  const float* Whf = (const float*)d_in[7];
  const float* bff = (const float*)d_in[8];
  const float* Wxo = (const float*)d_in[9];
  const float* Who = (const float*)d_in[10];
  const float* bo = (const float*)d_in[11];
  const float* Wxc = (const float*)d_in[12];
  const float* Whc = (const float*)d_in[13];
  const float* bc = (const float*)d_in[14];
  const float* fcW = (const float*)d_in[15];
  const float* fcb = (const float*)d_in[16];
  float* out = (float*)d_out;

  char* ws = (char*)d_ws;
  size_t off = 0;
  auto take = [&](size_t bytes) {
    char* p = ws + off;
    off += (bytes + 255) & ~(size_t)255;
    return p;
  };
  unsigned* bar = (unsigned*)take(16384 * 4);           // flags[256] (128B-strided)
  u16* inpb = (u16*)take((size_t)512 * 64 * 512 * 2);   // 32 MB
  u16* wxcT = (u16*)take((size_t)4096 * 512 * 2);       // 4 MB
  u16* whcT = (u16*)take((size_t)4096 * 1024 * 2);      // 8 MB
  u16* hbuf = (u16*)take((size_t)513 * 64 * 1024 * 2);  // 64 MB
  u16* xpb = (u16*)take((size_t)32768 * 4096 * 2);      // 256 MB (path A only)
  size_t needA = off;
  int useA = (ws_size >= needA) ? 1 : 0;

  k_cvt_in<<<8192, 256, 0, stream>>>(inputs, inpb);
  k_cvt_w<<<1024, 256, 0, stream>>>(Wxi, Wxf, Wxo, Wxc, 512, wxcT);
  k_cvt_w<<<2048, 256, 0, stream>>>(Whi, Whf, Who, Whc, 1024, whcT);
  k_init<<<256, 256, 0, stream>>>(H0, hbuf, bar);
  if (useA) {
    k_xp<<<dim3(512, 64), 256, 0, stream>>>(inpb, wxcT, xpb);
    k_recur<1><<<NWG, 512, 0, stream>>>(hbuf, whcT, wxcT, xpb, inpb, C0, bi, bff,
                                        bo, bc, out, bar);
  } else {
    k_recur<0><<<NWG, 512, 0, stream>>>(hbuf, whcT, wxcT, xpb, inpb, C0, bi, bff,
                                        bo, bc, out, bar);
  }
  k_pred<<<8192, 256, 0, stream>>>(hbuf, fcW, fcb, out);
}